// Round 3
// baseline (250.322 us; speedup 1.0000x reference)
//
#include <hip/hip_runtime.h>
#include <cstddef>

// SelfAttention MFMA v3. B=4, C=256, Cq=32, N=4096.
// out = gamma * (V @ softmax(clip(Q K^T/sqrt(32), +-5))^T) + x
//
// MFMA 16x16x32 bf16 layouts (HW-verified):
//   A-frag: lane holds A[m=lane&15][k=quad*8+j]  (16B contiguous in k)
//   B-frag: lane holds B[k=quad*8+j][n=lane&15]  (16B contiguous in k)
//   C/D   : lane holds D[row=quad*4+r][col=lane&15]
//
// attn computes S^T = K Q^T so D rows = m (keys): P written as packed b64,
// denominator per-lane (col = q).

#define BB 4
#define CC 256
#define CQ 32
#define NN 4096
#define TQ 64
#define TM 256
#define PSTR 264   // P_sh row stride (bf16): 528B rows, even bank spread

typedef __attribute__((ext_vector_type(8))) short short8;
typedef __attribute__((ext_vector_type(4))) float floatx4;
typedef __attribute__((ext_vector_type(4))) unsigned short ushortx4;
typedef __attribute__((ext_vector_type(8))) unsigned short ushortx8;

__device__ __forceinline__ unsigned short f2bf(float x) {
  union { float f; unsigned u; } v; v.f = x;
  unsigned r = v.u + 0x7FFFu + ((v.u >> 16) & 1u);   // RNE
  return (unsigned short)(r >> 16);
}

// ---------------- prep: W fp32 -> Wall bf16 [320][256] ----------------
__global__ __launch_bounds__(256) void prep_kernel(
    const float* __restrict__ Wq, const float* __restrict__ Wk,
    const float* __restrict__ Wv, unsigned short* __restrict__ Wall)
{
  int e = (blockIdx.x * 256 + threadIdx.x) * 4;   // 80 blocks -> 81920 elems
  int o = e >> 8, c = e & 255;
  const float* src = (o < 32) ? (Wq + o * 256 + c)
                   : (o < 64) ? (Wk + (o - 32) * 256 + c)
                              : (Wv + (o - 64) * 256 + c);
  float4 v = *(const float4*)src;
  ushortx4 pk;
  pk[0] = f2bf(v.x); pk[1] = f2bf(v.y); pk[2] = f2bf(v.z); pk[3] = f2bf(v.w);
  *(ushortx4*)(Wall + e) = pk;
}

// ---------------- transpose: x fp32 [b][c][n] -> xT bf16 [b][n][c] ----------
__global__ __launch_bounds__(256) void transpose_kernel(
    const float* __restrict__ x, unsigned short* __restrict__ xT)
{
  const int blk = blockIdx.x;          // 1024 = b(4) * ct(4) * nt(64)
  const int nt = blk & 63, ct = (blk >> 6) & 3, b = blk >> 8;
  const int c0 = ct * 64, n0 = nt * 64;
  const int t = threadIdx.x;
  __shared__ __align__(16) unsigned short ts[64 * 72];   // [n][c], pad 8

  const int rbase = t >> 4;
  const int n4 = (t & 15) * 4;
  #pragma unroll
  for (int u = 0; u < 4; ++u) {
    int row = rbase + 16 * u;   // c-local
    float4 v = *(const float4*)(x + (size_t)(b * CC + c0 + row) * NN + n0 + n4);
    ts[(n4 + 0) * 72 + row] = f2bf(v.x);
    ts[(n4 + 1) * 72 + row] = f2bf(v.y);
    ts[(n4 + 2) * 72 + row] = f2bf(v.z);
    ts[(n4 + 3) * 72 + row] = f2bf(v.w);
  }
  __syncthreads();
  const int c4 = (t & 15) * 4;
  #pragma unroll
  for (int u = 0; u < 4; ++u) {
    int nl = rbase + 16 * u;    // n-local
    ushortx4 vv = *(const ushortx4*)(ts + nl * 72 + c4);
    *(ushortx4*)(xT + (size_t)(b * NN + n0 + nl) * CC + c0 + c4) = vv;
  }
}

// ---------------- proj: both operands direct from global, no LDS ------------
// A = xT (rows=n), B = Wall^T (cols=o). D[row=n][col=o].
__global__ __launch_bounds__(256, 1) void proj_kernel(
    const unsigned short* __restrict__ xT, const unsigned short* __restrict__ Wall,
    const float* __restrict__ bq, const float* __restrict__ bk,
    const float* __restrict__ bv,
    unsigned short* __restrict__ qo, unsigned short* __restrict__ ko,
    unsigned short* __restrict__ vo)
{
  const int b  = blockIdx.x >> 6;
  const int n0 = (blockIdx.x & 63) * 64;
  const int t  = threadIdx.x;
  const int w = t >> 6, lane = t & 63, quad = lane >> 4, l16 = lane & 15;

  floatx4 acc[5][4];   // [fo][fn]
  #pragma unroll
  for (int fo = 0; fo < 5; ++fo)
    #pragma unroll
    for (int fn = 0; fn < 4; ++fn) acc[fo][fn] = (floatx4){0.f, 0.f, 0.f, 0.f};

  const unsigned short* xb = xT + (size_t)(b * NN + n0) * CC;

  #pragma unroll 1
  for (int ks = 0; ks < 8; ++ks) {
    const int k0 = ks * 32 + quad * 8;
    short8 afr[4];
    #pragma unroll
    for (int fn = 0; fn < 4; ++fn)
      afr[fn] = *(const short8*)(xb + (size_t)(16 * fn + l16) * CC + k0);
    short8 bfr[5];
    #pragma unroll
    for (int fo = 0; fo < 5; ++fo)
      bfr[fo] = *(const short8*)(Wall + (size_t)(80 * w + 16 * fo + l16) * CC + k0);
    #pragma unroll
    for (int fo = 0; fo < 5; ++fo)
      #pragma unroll
      for (int fn = 0; fn < 4; ++fn)
        acc[fo][fn] = __builtin_amdgcn_mfma_f32_16x16x32_bf16(
            afr[fn], bfr[fo], acc[fo][fn], 0, 0, 0);
  }

  #pragma unroll
  for (int fo = 0; fo < 5; ++fo) {
    const int ob = 80 * w + 16 * fo;   // wave-uniform, 16-aligned: no straddle
    const float bias = (ob < 32) ? bq[ob + l16]
                     : (ob < 64) ? bk[ob - 32 + l16]
                                 : bv[ob - 64 + l16];
    #pragma unroll
    for (int fn = 0; fn < 4; ++fn) {
      if (ob < 64) {                       // q or k: [n][32]
        unsigned short* dst = (ob < 32) ? qo : ko;
        const int o = ((ob < 32) ? ob : ob - 32) + l16;
        #pragma unroll
        for (int r = 0; r < 4; ++r) {
          const int n = n0 + 16 * fn + quad * 4 + r;
          dst[(size_t)(b * NN + n) * CQ + o] = f2bf(acc[fo][fn][r] + bias);
        }
      } else {                             // v: [c][n], 4 consecutive n
        ushortx4 pk;
        #pragma unroll
        for (int r = 0; r < 4; ++r) pk[r] = f2bf(acc[fo][fn][r] + bias);
        const int o = ob - 64 + l16;
        *(ushortx4*)(vo + (size_t)(b * CC + o) * NN + n0 + 16 * fn + quad * 4) = pk;
      }
    }
  }
}

// ---------------- fused attention, TM=256 ----------------
__global__ __launch_bounds__(512, 2) void attn_kernel(
    const unsigned short* __restrict__ qg, const unsigned short* __restrict__ kg,
    const unsigned short* __restrict__ vg, const float* __restrict__ x,
    const float* __restrict__ gamma, float* __restrict__ out)
{
  const int blk = blockIdx.x;
  const int xcd = blk & 7;                       // pin batch to XCD pair (L2)
  const int b   = xcd >> 1;
  const int n0  = ((blk >> 3) + 32 * (xcd & 1)) * TQ;
  const int t = threadIdx.x;
  const int w = t >> 6, lane = t & 63, quad = lane >> 4, l16 = lane & 15;

  __shared__ __align__(16) unsigned short k_sh[TM * CQ];    // 16 KB, packed
  __shared__ __align__(16) unsigned short P_sh[TQ * PSTR];  // 33.8 KB
  __shared__ float l_part[8][TQ];

  const int c0w = 64 * (w & 3);    // PV: channel group
  const int q0w = 32 * (w >> 2);   // PV: query half

  // Q fragments (B operand), all 4, held in regs
  short8 qf[4];
  #pragma unroll
  for (int f = 0; f < 4; ++f)
    qf[f] = *(const short8*)(qg + (size_t)(b * NN + n0 + 16 * f + l16) * CQ
                             + quad * 8);

  floatx4 acc[4][2];   // [fc][fq]
  #pragma unroll
  for (int fc = 0; fc < 4; ++fc)
    #pragma unroll
    for (int fq = 0; fq < 2; ++fq) acc[fc][fq] = (floatx4){0.f, 0.f, 0.f, 0.f};
  float dsum[4] = {0.f, 0.f, 0.f, 0.f};

  const unsigned short* kgb = kg + (size_t)b * NN * CQ;
  const unsigned short* vgb = vg + (size_t)b * CC * NN;
  const floatx4 zero4 = {0.f, 0.f, 0.f, 0.f};
  const float scale = 0.17677669529663687f;   // 1/sqrt(32)

  #pragma unroll 1
  for (int m0 = 0; m0 < NN; m0 += TM) {
    // stage K tile: 16 KB, packed [m][32], contiguous global == LDS
    {
      const unsigned short* src = kgb + (size_t)m0 * CQ;
      #pragma unroll
      for (int u = 0; u < 2; ++u) {
        const int cidx = t + 512 * u;
        *(ushortx8*)(k_sh + cidx * 8) = *(const ushortx8*)(src + cidx * 8);
      }
    }
    __syncthreads();

    // scores: S^T = K Q^T. wave w: m-frags {2w, 2w+1} x all 4 q-frags
    #pragma unroll
    for (int e = 0; e < 2; ++e) {
      const int mf = 2 * w + e;
      const short8 kfrag = *(const short8*)(k_sh + (mf * 16 + l16) * CQ + quad * 8);
      #pragma unroll
      for (int qfi = 0; qfi < 4; ++qfi) {
        floatx4 s = __builtin_amdgcn_mfma_f32_16x16x32_bf16(
            kfrag, qf[qfi], zero4, 0, 0, 0);
        ushortx4 pk;
        #pragma unroll
        for (int r = 0; r < 4; ++r) {
          float ev = fminf(fmaxf(s[r] * scale, -5.f), 5.f);
          float p = __expf(ev);
          dsum[qfi] += p;
          pk[r] = f2bf(p);
        }
        // D row = m-local (quad*4+r), col = q (l16): packed 8B write
        *(ushortx4*)(P_sh + (qfi * 16 + l16) * PSTR + mf * 16 + quad * 4) = pk;
      }
    }
    __syncthreads();

    // PV: O[c][q] += V[c][m] P[q][m]. A = V (global), B = P (LDS b128)
    #pragma unroll 2
    for (int ks = 0; ks < 8; ++ks) {
      const int mk = m0 + ks * 32 + quad * 8;
      short8 vfr[4];
      #pragma unroll
      for (int fc = 0; fc < 4; ++fc)
        vfr[fc] = *(const short8*)(vgb + (size_t)(c0w + 16 * fc + l16) * NN + mk);
      short8 pfr[2];
      #pragma unroll
      for (int fq = 0; fq < 2; ++fq)
        pfr[fq] = *(const short8*)(P_sh + (q0w + 16 * fq + l16) * PSTR
                                   + ks * 32 + quad * 8);
      #pragma unroll
      for (int fc = 0; fc < 4; ++fc)
        #pragma unroll
        for (int fq = 0; fq < 2; ++fq)
          acc[fc][fq] = __builtin_amdgcn_mfma_f32_16x16x32_bf16(
              vfr[fc], pfr[fq], acc[fc][fq], 0, 0, 0);
    }
  }

  // denominator: lane col = q, reduce across quads (lanes sharing l16)
  #pragma unroll
  for (int qfi = 0; qfi < 4; ++qfi) {
    dsum[qfi] += __shfl_xor(dsum[qfi], 16);
    dsum[qfi] += __shfl_xor(dsum[qfi], 32);
  }
  if (lane < 16) {
    #pragma unroll
    for (int qfi = 0; qfi < 4; ++qfi)
      l_part[w][qfi * 16 + lane] = dsum[qfi];
  }
  __syncthreads();

  // epilogue: out = gamma*(acc/l) + x
  const float g = gamma[0];
  #pragma unroll
  for (int fq = 0; fq < 2; ++fq) {
    const int qq = q0w + 16 * fq + l16;
    float l = 0.f;
    #pragma unroll
    for (int j = 0; j < 8; ++j) l += l_part[j][qq];
    const float gl = g / l;
    #pragma unroll
    for (int fc = 0; fc < 4; ++fc) {
      #pragma unroll
      for (int r = 0; r < 4; ++r) {
        const size_t a =
            (size_t)(b * CC + c0w + 16 * fc + quad * 4 + r) * NN + n0 + qq;
        out[a] = fmaf(acc[fc][fq][r], gl, x[a]);
      }
    }
  }
}

extern "C" void kernel_launch(void* const* d_in, const int* in_sizes, int n_in,
                              void* d_out, int out_size, void* d_ws, size_t ws_size,
                              hipStream_t stream) {
  const float* x     = (const float*)d_in[0];
  const float* Wq    = (const float*)d_in[1];
  const float* bq    = (const float*)d_in[2];
  const float* Wk    = (const float*)d_in[3];
  const float* bk    = (const float*)d_in[4];
  const float* Wv    = (const float*)d_in[5];
  const float* bv    = (const float*)d_in[6];
  const float* gamma = (const float*)d_in[7];
  float* out = (float*)d_out;

  unsigned short* ws = (unsigned short*)d_ws;
  unsigned short* qb   = ws;                                   // 1 MB
  unsigned short* kb   = qb + (size_t)BB * NN * CQ;            // 1 MB
  unsigned short* vb   = kb + (size_t)BB * NN * CQ;            // 8 MB
  unsigned short* Wall = vb + (size_t)BB * CC * NN;            // 160 KB
  unsigned short* xT   = Wall + 320 * 256;                     // 8 MB

  prep_kernel<<<80, 256, 0, stream>>>(Wq, Wk, Wv, Wall);
  transpose_kernel<<<BB * 4 * (NN / 64), 256, 0, stream>>>(x, xT);
  proj_kernel<<<BB * (NN / 64), 256, 0, stream>>>(xT, Wall, bq, bk, bv,
                                                  qb, kb, vb);
  attn_kernel<<<BB * (NN / TQ), 512, 0, stream>>>(qb, kb, vb, x, gamma, out);
}

// Round 4
// 154.473 us; speedup vs baseline: 1.6205x; 1.6205x over previous
//
#include <hip/hip_runtime.h>
#include <cstddef>
#include <cstdint>

// SelfAttention MFMA v4. B=4, C=256, Cq=32, N=4096.
// out = gamma * (V @ softmax(clip(Q K^T/sqrt(32), +-5))^T) + x
//
// MFMA 16x16x32 bf16 layouts (HW-verified):
//   A-frag: lane holds A[m=lane&15][k=quad*8+j]  (16B contiguous in k)
//   B-frag: lane holds B[k=quad*8+j][n=lane&15]  (16B contiguous in k)
//   C/D   : lane holds D[row=quad*4+r][col=lane&15]
//
// Key changes vs v3 (157us attn, 12% MfmaUtil):
//  - V stored FRAGMENT-MAJOR (Vf): attention V loads are coalesced 1KB each
//  - attn: 1024 thr (16 waves/CU), V reg-prefetch, K via global_load_lds
//  - proj: merged transpose, both operands contiguous; 512 blocks

#define BB 4
#define CC 256
#define CQ 32
#define NN 4096
#define TQ 64
#define TM 256
#define PSTR 264   // P_sh row stride, shorts (132 dw == 4 mod 32: 2-way, free)
#define CSTR 264   // proj xs row stride
#define VTSTR 40   // proj vt row stride

typedef __attribute__((ext_vector_type(8))) short short8;
typedef __attribute__((ext_vector_type(4))) float floatx4;
typedef __attribute__((ext_vector_type(4))) unsigned short ushortx4;

__device__ __forceinline__ unsigned short f2bf(float x) {
  union { float f; unsigned u; } v; v.f = x;
  unsigned r = v.u + 0x7FFFu + ((v.u >> 16) & 1u);   // RNE
  return (unsigned short)(r >> 16);
}

__device__ __forceinline__ void glds16(const unsigned short* g, unsigned short* l) {
  __builtin_amdgcn_global_load_lds(
      (const __attribute__((address_space(1))) unsigned int*)g,
      (__attribute__((address_space(3))) unsigned int*)l, 16, 0, 0);
}

// ---------------- prep: W fp32 -> Wall bf16 [320][256] ----------------
__global__ __launch_bounds__(256) void prep_kernel(
    const float* __restrict__ Wq, const float* __restrict__ Wk,
    const float* __restrict__ Wv, unsigned short* __restrict__ Wall)
{
  int e = (blockIdx.x * 256 + threadIdx.x) * 4;   // 80 blocks -> 81920 elems
  int o = e >> 8, c = e & 255;
  const float* src = (o < 32) ? (Wq + o * 256 + c)
                   : (o < 64) ? (Wk + (o - 32) * 256 + c)
                              : (Wv + (o - 64) * 256 + c);
  float4 v = *(const float4*)src;
  ushortx4 pk;
  pk[0] = f2bf(v.x); pk[1] = f2bf(v.y); pk[2] = f2bf(v.z); pk[3] = f2bf(v.w);
  *(ushortx4*)(Wall + e) = pk;
}

// ---------------- proj: q[n][32], k[n][32], Vf fragment-major ---------------
// Vf frag (M32, fc): lane l holds V[fc*16+(l&15)][M32*32+(l>>4)*8+j], j=0..7
__global__ __launch_bounds__(256, 4) void proj_kernel(
    const float* __restrict__ x, const unsigned short* __restrict__ Wall,
    const float* __restrict__ bq, const float* __restrict__ bk,
    const float* __restrict__ bv,
    unsigned short* __restrict__ qo, unsigned short* __restrict__ ko,
    unsigned short* __restrict__ Vf)
{
  const int blk = blockIdx.x;          // 512 = b(4) * nt(128)
  const int b = blk >> 7, nt = blk & 127;
  const int n0 = nt * 32;
  const int t = threadIdx.x;
  const int w = t >> 6, lane = t & 63, quad = lane >> 4, l16 = lane & 15;

  __shared__ __align__(16) unsigned short xs[32 * CSTR];   // [n][c] bf16
  __shared__ __align__(16) unsigned short vt[CC * VTSTR];  // [c][n] bf16

  // stage x tile [c 256][n 32] -> xs[n][c] (coalesced read, scattered write)
  #pragma unroll
  for (int u = 0; u < 8; ++u) {
    int idx = t + 256 * u;             // 0..2047 float4s
    int c = idx >> 3, n4 = (idx & 7) * 4;
    float4 v = *(const float4*)(x + ((size_t)(b * CC + c)) * NN + n0 + n4);
    xs[(n4 + 0) * CSTR + c] = f2bf(v.x);
    xs[(n4 + 1) * CSTR + c] = f2bf(v.y);
    xs[(n4 + 2) * CSTR + c] = f2bf(v.z);
    xs[(n4 + 3) * CSTR + c] = f2bf(v.w);
  }
  __syncthreads();

  floatx4 acc[5][2];
  #pragma unroll
  for (int fo = 0; fo < 5; ++fo)
    #pragma unroll
    for (int fn = 0; fn < 2; ++fn) acc[fo][fn] = (floatx4){0.f, 0.f, 0.f, 0.f};

  #pragma unroll 1
  for (int ks = 0; ks < 8; ++ks) {
    const int k0 = ks * 32 + quad * 8;
    short8 afr[2];
    #pragma unroll
    for (int fn = 0; fn < 2; ++fn)
      afr[fn] = *(const short8*)(xs + (16 * fn + l16) * CSTR + k0);
    short8 bfr[5];
    #pragma unroll
    for (int fo = 0; fo < 5; ++fo)
      bfr[fo] = *(const short8*)(Wall + (size_t)(80 * w + 16 * fo + l16) * CC + k0);
    #pragma unroll
    for (int fo = 0; fo < 5; ++fo)
      #pragma unroll
      for (int fn = 0; fn < 2; ++fn)
        acc[fo][fn] = __builtin_amdgcn_mfma_f32_16x16x32_bf16(
            afr[fn], bfr[fo], acc[fo][fn], 0, 0, 0);
  }

  // epilogue: D[row = n-local (quad*4+r)][col = o (l16)]
  #pragma unroll
  for (int fo = 0; fo < 5; ++fo) {
    const int ob = 80 * w + 16 * fo;   // wave-uniform, never straddles q/k/v
    const float bias = (ob < 32) ? bq[ob + l16]
                     : (ob < 64) ? bk[ob - 32 + l16]
                                 : bv[ob - 64 + l16];
    #pragma unroll
    for (int fn = 0; fn < 2; ++fn) {
      if (ob < 64) {                       // q or k: [n][32]
        unsigned short* dst = (ob < 32) ? qo : ko;
        const int o = ((ob < 32) ? ob : ob - 32) + l16;
        #pragma unroll
        for (int r = 0; r < 4; ++r) {
          const int n = n0 + 16 * fn + quad * 4 + r;
          dst[(size_t)(b * NN + n) * CQ + o] = f2bf(acc[fo][fn][r] + bias);
        }
      } else {                             // v -> vt[c][n-local]
        const int c = ob - 64 + l16;
        ushortx4 pk;
        #pragma unroll
        for (int r = 0; r < 4; ++r) pk[r] = f2bf(acc[fo][fn][r] + bias);
        *(ushortx4*)(vt + c * VTSTR + 16 * fn + quad * 4) = pk;
      }
    }
  }
  __syncthreads();

  // Vf write: 16 frags for M32 = nt; wave w owns fc = 4w..4w+3
  #pragma unroll
  for (int j = 0; j < 4; ++j) {
    const int fc = 4 * w + j;
    short8 v8 = *(const short8*)(vt + (fc * 16 + l16) * VTSTR + quad * 8);
    *(short8*)(Vf + (((size_t)b * 128 + nt) * 16 + fc) * 512 + lane * 8) = v8;
  }
}

// ---------------- fused attention: 1024 thr, TM=256 ----------------
__global__ __launch_bounds__(1024, 4) void attn_kernel(
    const unsigned short* __restrict__ qg, const unsigned short* __restrict__ kg,
    const unsigned short* __restrict__ Vf, const float* __restrict__ x,
    const float* __restrict__ gamma, float* __restrict__ out)
{
  const int blk = blockIdx.x;                     // 256
  const int b  = (blk & 7) >> 1;                  // XCD-pinned batch
  const int nt = ((blk >> 3) << 1) | (blk & 1);   // 0..63
  const int n0 = nt * TQ;
  const int t = threadIdx.x;
  const int w = t >> 6, lane = t & 63, quad = lane >> 4, l16 = lane & 15;
  const int cg = w & 3, qh = (w >> 2) & 1, mh = w >> 3;

  __shared__ __align__(16) unsigned short k_sh[TM * CQ];    // 16 KB, packed
  __shared__ __align__(16) unsigned short P_sh[TQ * PSTR];  // 33.8 KB
  __shared__ float l_part[16][TQ];
  __shared__ float l_tot[TQ];
  __shared__ float red[8][64][33];                           // 67.6 KB

  const unsigned short* kgb = kg + (size_t)b * NN * CQ;
  const unsigned short* Vfb = Vf + (size_t)b * 128 * 16 * 512;
  unsigned short* kdst = k_sh + (w << 9);         // wave-uniform LDS base

  // Q fragments (B operand), all 4, held in regs
  short8 qf[4];
  #pragma unroll
  for (int f = 0; f < 4; ++f)
    qf[f] = *(const short8*)(qg + (size_t)(b * NN + n0 + 16 * f + l16) * CQ
                             + quad * 8);

  floatx4 acc[4][2];   // [fc-local][fq]
  #pragma unroll
  for (int j = 0; j < 4; ++j)
    #pragma unroll
    for (int fq = 0; fq < 2; ++fq) acc[j][fq] = (floatx4){0.f, 0.f, 0.f, 0.f};
  float dsum[4] = {0.f, 0.f, 0.f, 0.f};

  glds16(kgb + t * 8, kdst);                       // stage tile 0
  __syncthreads();

  const floatx4 zero4 = {0.f, 0.f, 0.f, 0.f};
  const float scale = 0.17677669529663687f;        // 1/sqrt(32)

  #pragma unroll 1
  for (int i = 0; i < 16; ++i) {
    // prefetch V first half (tile i, local ks {4mh, 4mh+1}), coalesced 1KB
    const size_t fbase = (size_t)((i * 8 + 4 * mh) * 16) * 512;
    short8 va[8];
    #pragma unroll
    for (int kk = 0; kk < 2; ++kk)
      #pragma unroll
      for (int j = 0; j < 4; ++j)
        va[kk * 4 + j] = *(const short8*)(
            Vfb + fbase + ((size_t)(kk * 16 + 4 * cg + j)) * 512 + lane * 8);

    // scores: S^T = K Q^T; wave w owns m-frag w
    const short8 kfrag = *(const short8*)(k_sh + (w * 16 + l16) * CQ + quad * 8);
    #pragma unroll
    for (int qfi = 0; qfi < 4; ++qfi) {
      floatx4 s = __builtin_amdgcn_mfma_f32_16x16x32_bf16(
          kfrag, qf[qfi], zero4, 0, 0, 0);
      ushortx4 pk;
      #pragma unroll
      for (int r = 0; r < 4; ++r) {
        float ev = fminf(fmaxf(s[r] * scale, -5.f), 5.f);
        float p = __expf(ev);
        dsum[qfi] += p;
        pk[r] = f2bf(p);
      }
      *(ushortx4*)(P_sh + (qfi * 16 + l16) * PSTR + w * 16 + quad * 4) = pk;
    }
    __syncthreads();   // P ready; k_sh reads done; va landed

    // async K prefetch for tile i+1 (lands by the end-of-loop barrier)
    if (i < 15) glds16(kgb + (size_t)(i + 1) * TM * CQ + t * 8, kdst);

    // prefetch V second half (local ks {4mh+2, 4mh+3})
    short8 vb[8];
    #pragma unroll
    for (int kk = 0; kk < 2; ++kk)
      #pragma unroll
      for (int j = 0; j < 4; ++j)
        vb[kk * 4 + j] = *(const short8*)(
            Vfb + fbase + ((size_t)((2 + kk) * 16 + 4 * cg + j)) * 512 + lane * 8);

    // PV: O[c][q] += V[c][m] P[q][m]
    #pragma unroll
    for (int ksi = 0; ksi < 4; ++ksi) {
      const int mc = (4 * mh + ksi) * 32;
      const short8 p0 = *(const short8*)(
          P_sh + ((2 * qh + 0) * 16 + l16) * PSTR + mc + quad * 8);
      const short8 p1 = *(const short8*)(
          P_sh + ((2 * qh + 1) * 16 + l16) * PSTR + mc + quad * 8);
      const short8* vv = (ksi < 2) ? &va[ksi * 4] : &vb[(ksi - 2) * 4];
      #pragma unroll
      for (int j = 0; j < 4; ++j) {
        acc[j][0] = __builtin_amdgcn_mfma_f32_16x16x32_bf16(vv[j], p0, acc[j][0], 0, 0, 0);
        acc[j][1] = __builtin_amdgcn_mfma_f32_16x16x32_bf16(vv[j], p1, acc[j][1], 0, 0, 0);
      }
    }
    __syncthreads();   // P reads done; k_sh(i+1) landed
  }

  // denominator: reduce over quads (m), per (w, qf, l16)
  #pragma unroll
  for (int qfi = 0; qfi < 4; ++qfi) {
    dsum[qfi] += __shfl_xor(dsum[qfi], 16);
    dsum[qfi] += __shfl_xor(dsum[qfi], 32);
  }
  if (lane < 16) {
    #pragma unroll
    for (int qfi = 0; qfi < 4; ++qfi)
      l_part[w][qfi * 16 + lane] = dsum[qfi];
  }
  __syncthreads();
  if (t < TQ) {
    float s = 0.f;
    #pragma unroll
    for (int j = 0; j < 16; ++j) s += l_part[j][t];
    l_tot[t] = s;
  }
  // m-half partial exchange: waves mh=1 -> LDS
  if (mh == 1) {
    #pragma unroll
    for (int j = 0; j < 4; ++j)
      #pragma unroll
      for (int fq = 0; fq < 2; ++fq)
        #pragma unroll
        for (int r = 0; r < 4; ++r)
          red[w - 8][lane][j * 8 + fq * 4 + r] = acc[j][fq][r];
  }
  __syncthreads();
  if (mh == 0) {
    const float g = gamma[0];
    #pragma unroll
    for (int fq = 0; fq < 2; ++fq) {
      const int q = (2 * qh + fq) * 16 + l16;
      const float gl = g / l_tot[q];
      #pragma unroll
      for (int j = 0; j < 4; ++j) {
        #pragma unroll
        for (int r = 0; r < 4; ++r) {
          const float v = acc[j][fq][r] + red[w][lane][j * 8 + fq * 4 + r];
          const size_t a =
              (size_t)(b * CC + (4 * cg + j) * 16 + quad * 4 + r) * NN + n0 + q;
          out[a] = fmaf(v, gl, x[a]);
        }
      }
    }
  }
}

extern "C" void kernel_launch(void* const* d_in, const int* in_sizes, int n_in,
                              void* d_out, int out_size, void* d_ws, size_t ws_size,
                              hipStream_t stream) {
  const float* x     = (const float*)d_in[0];
  const float* Wq    = (const float*)d_in[1];
  const float* bq    = (const float*)d_in[2];
  const float* Wk    = (const float*)d_in[3];
  const float* bk    = (const float*)d_in[4];
  const float* Wv    = (const float*)d_in[5];
  const float* bv    = (const float*)d_in[6];
  const float* gamma = (const float*)d_in[7];
  float* out = (float*)d_out;

  unsigned short* ws = (unsigned short*)d_ws;
  unsigned short* qb   = ws;                                   // 1 MB
  unsigned short* kb   = qb + (size_t)BB * NN * CQ;            // 1 MB
  unsigned short* Vf   = kb + (size_t)BB * NN * CQ;            // 8 MB
  unsigned short* Wall = Vf + (size_t)BB * 128 * 16 * 512;     // 160 KB

  prep_kernel<<<80, 256, 0, stream>>>(Wq, Wk, Wv, Wall);
  proj_kernel<<<BB * 128, 256, 0, stream>>>(x, Wall, bq, bk, bv, qb, kb, Vf);
  attn_kernel<<<BB * (NN / TQ), 1024, 0, stream>>>(qb, kb, Vf, x, gamma, out);
}